// Round 7
// baseline (21.136 us; speedup 1.0000x reference)
//
#include <hip/hip_runtime.h>

// Fused Quanvolution + conv + FC + log_softmax via MFMA, MI355X (gfx950).
//
// Quantum features in closed form (Heisenberg-picture, verified R1-R6):
//   z0 = cos(x00); z1 = cos(x01); z2 = cos(x00)*cos(x10)
//   z3 = 0.5*((c1*c3 - s3) - c0*c2*(c1*c3 + s3))
//
// R7 vs R6 (19.6 us): strip the last structurally-removable work.
//  - NO x LDS staging (R4==R5 proved staging neutral): pixel float2 loads go
//    direct from global, but ALL hoisted before compute (R6's pipelining win).
//    Removes ~45 insts/thread, one barrier, 50 KB LDS.
//  - B-prep (load+pack) placed between pixel-load issue and pixel use: its
//    ~35 L2-hot loads + packing hide the pixel HBM latency.
//  - Prescale by 1/2pi applied in-register (4 v_mul/patch); conv weights
//    pre-scaled by 2pi; z3's 0.5 folded into B slot 7 (both from R6).
//  - LDS = 8 KB reduce buffer only.
// MFMA mapping identical to R4-R6 (refcheck-verified): lane=(img=l&15,
// slot=l>>4); A k-slice = slot's patch, 8 feats; same permutation on A/B.
//
// Decision rule: three disjoint structures (R4/R5/R6) all hit 19.6-21.2 us
// while bottom-up arithmetic says ~5-6 us; if R7 also lands >=18 us the
// residual is a fixed external floor and we are done.

typedef _Float16 f16x8 __attribute__((ext_vector_type(8)));
typedef float    f32x4 __attribute__((ext_vector_type(4)));
typedef unsigned int u32x4 __attribute__((ext_vector_type(4)));

#define INV2PI 0.15915494309189535f
#define TWOPI  6.283185307179586f

__global__ __launch_bounds__(512, 4) void quanv_mfma(
    const float* __restrict__ x,       // [B][784]
    const float* __restrict__ conv_w,  // [4][1][2][2]
    const float* __restrict__ conv_b,  // [4]
    const float* __restrict__ fc_w,    // [10][1568]
    const float* __restrict__ fc_b,    // [10]
    float* __restrict__ out,           // [B][10]
    int B)
{
    __shared__ float red[8][16][16];   // 8 KB wave partials

    const int tid  = threadIdx.x;
    const int wid  = tid >> 6;
    const int lane = tid & 63;
    const int l15  = lane & 15;        // A row (img) AND B col (o)
    const int slot = lane >> 4;        // k-slice = patch within 4-patch group
    const int b0   = blockIdx.x * 16;

    // ---- phase 0: issue ALL pixel loads (direct global, hoisted) ----
    const float* xi = x + (size_t)(b0 + l15) * 784;
    float2 pxa[7], pxb[7];
#pragma unroll
    for (int j = 0; j < 6; ++j) {
        const int p   = ((wid + (j << 3)) << 2) + slot;
        const int pi  = p / 14;
        const int pj  = p - pi * 14;
        const int off = pi * 56 + pj * 2;
        pxa[j] = *reinterpret_cast<const float2*>(xi + off);
        pxb[j] = *reinterpret_cast<const float2*>(xi + off + 28);
    }
    if (wid == 0) {                    // g=48 exists only for wave 0
        const int p   = 192 + slot;    // pi=13
        const int off = 13 * 56 + (p - 182) * 2;
        pxa[6] = *reinterpret_cast<const float2*>(xi + off);
        pxb[6] = *reinterpret_cast<const float2*>(xi + off + 28);
    }

    // ---- phase 1: B-operand fragments (L2-hot loads + pack hide phase 0) ----
    const int   o   = l15;
    const int   oc  = (o < 10) ? o : 9;
    const float msk = (o < 10) ? 1.f : 0.f;
    const float* wr = fc_w + oc * 1568;

    f16x8 bw[7];
#pragma unroll
    for (int j = 0; j < 7; ++j) {
        const int g = wid + (j << 3);
        if (g < 49) {
            const int p = (g << 2) + slot;
            const float w0 = wr[p]       * msk;
            const float w1 = wr[196 + p] * msk;
            const float w2 = wr[392 + p] * msk;
            const float w3 = wr[588 + p] * msk;
            const float4 wq = *reinterpret_cast<const float4*>(wr + 784 + p * 4);
            u32x4 wu;
            wu[0] = __builtin_bit_cast(unsigned int, __builtin_amdgcn_cvt_pkrtz(w0, w1));
            wu[1] = __builtin_bit_cast(unsigned int, __builtin_amdgcn_cvt_pkrtz(w2, w3));
            wu[2] = __builtin_bit_cast(unsigned int, __builtin_amdgcn_cvt_pkrtz(wq.x * msk, wq.y * msk));
            wu[3] = __builtin_bit_cast(unsigned int, __builtin_amdgcn_cvt_pkrtz(wq.z * msk, wq.w * (0.5f * msk)));
            bw[j] = __builtin_bit_cast(f16x8, wu);
        } else {
            u32x4 z = {0u, 0u, 0u, 0u};
            bw[j] = __builtin_bit_cast(f16x8, z);
        }
    }

    // uniform conv tensors -> scalar regs; 2pi folded (compensates prescale)
    float cw[16], cb[4];
#pragma unroll
    for (int i = 0; i < 16; ++i) cw[i] = conv_w[i] * TWOPI;
#pragma unroll
    for (int i = 0; i < 4; ++i) cb[i] = conv_b[i];

    // ---- phase 2: pure-register compute loop ----
    f32x4 acc = {0.f, 0.f, 0.f, 0.f};

#define BODY(j)                                                                 \
    {                                                                           \
        const float x00 = pxa[j].x * INV2PI, x01 = pxa[j].y * INV2PI;           \
        const float x10 = pxb[j].x * INV2PI, x11 = pxb[j].y * INV2PI;           \
        const float ft0 = fmaf(x00, cw[0],  fmaf(x01, cw[1],  fmaf(x10, cw[2],  fmaf(x11, cw[3],  cb[0])))); \
        const float ft1 = fmaf(x00, cw[4],  fmaf(x01, cw[5],  fmaf(x10, cw[6],  fmaf(x11, cw[7],  cb[1])))); \
        const float ft2 = fmaf(x00, cw[8],  fmaf(x01, cw[9],  fmaf(x10, cw[10], fmaf(x11, cw[11], cb[2])))); \
        const float ft3 = fmaf(x00, cw[12], fmaf(x01, cw[13], fmaf(x10, cw[14], fmaf(x11, cw[15], cb[3])))); \
        const float c0 = __builtin_amdgcn_cosf(x00);                            \
        const float c1 = __builtin_amdgcn_cosf(x01);                            \
        const float c2 = __builtin_amdgcn_cosf(x10);                            \
        const float s3 = __builtin_amdgcn_sinf(x11);                            \
        const float c3 = __builtin_amdgcn_cosf(x11);                            \
        const float t  = c0 * c2;                                               \
        const float u  = c1 * c3;                                               \
        const float z3 = fmaf(-t, u + s3, u - s3); /* 0.5 folded into B */      \
        u32x4 au;                                                               \
        au[0] = __builtin_bit_cast(unsigned int, __builtin_amdgcn_cvt_pkrtz(ft0, ft1)); \
        au[1] = __builtin_bit_cast(unsigned int, __builtin_amdgcn_cvt_pkrtz(ft2, ft3)); \
        au[2] = __builtin_bit_cast(unsigned int, __builtin_amdgcn_cvt_pkrtz(c0, c1));   \
        au[3] = __builtin_bit_cast(unsigned int, __builtin_amdgcn_cvt_pkrtz(t, z3));    \
        acc = __builtin_amdgcn_mfma_f32_16x16x32_f16(__builtin_bit_cast(f16x8, au), bw[j], acc, 0, 0, 0); \
    }

    BODY(0) BODY(1) BODY(2) BODY(3) BODY(4) BODY(5)
    if (wid == 0) BODY(6)
#undef BODY

    // ---- partial C -> LDS: lane holds C[row=slot*4+r][col=l15] = [img][o]
#pragma unroll
    for (int r = 0; r < 4; ++r)
        red[wid][slot * 4 + r][l15] = acc[r];
    __syncthreads();

    // ---- sum 8 wave-partials: thread t owns cell (row=t>>4, col=t&15)
    if (tid < 256) {
        const int row = tid >> 4, col = tid & 15;
        float s = 0.f;
#pragma unroll
        for (int w = 0; w < 8; ++w) s += red[w][row][col];
        red[0][row][col] = s;
    }
    __syncthreads();

    // ---- log_softmax + store: thread im handles image b0+im ----
    if (tid < 16) {
        const int im = tid;
        if (b0 + im < B) {
            float lg[10];
#pragma unroll
            for (int j = 0; j < 10; ++j) lg[j] = red[0][im][j] + fc_b[j];
            float mx = lg[0];
#pragma unroll
            for (int j = 1; j < 10; ++j) mx = fmaxf(mx, lg[j]);
            float se = 0.f;
#pragma unroll
            for (int j = 0; j < 10; ++j) se += __expf(lg[j] - mx);
            const float lse = __logf(se) + mx;
            float* op = out + (size_t)(b0 + im) * 10;
#pragma unroll
            for (int j = 0; j < 10; ++j) op[j] = lg[j] - lse;
        }
    }
}

extern "C" void kernel_launch(void* const* d_in, const int* in_sizes, int n_in,
                              void* d_out, int out_size, void* d_ws, size_t ws_size,
                              hipStream_t stream) {
    const float* x      = (const float*)d_in[0];
    const float* conv_w = (const float*)d_in[1];
    const float* conv_b = (const float*)d_in[2];
    const float* fc_w   = (const float*)d_in[3];
    const float* fc_b   = (const float*)d_in[4];
    float* out = (float*)d_out;

    const int B = in_sizes[0] / 784;           // 8192
    const int blocks = (B + 15) / 16;          // 16 images per block
    quanv_mfma<<<blocks, 512, 0, stream>>>(x, conv_w, conv_b, fc_w, fc_b, out, B);
}